// Round 5
// baseline (224.499 us; speedup 1.0000x reference)
//
#include <hip/hip_runtime.h>
#include <hip/hip_bf16.h>
#include <math.h>

// dtypes for MFMA
typedef __bf16 bf16x8 __attribute__((ext_vector_type(8)));
typedef float  f32x16 __attribute__((ext_vector_type(16)));

// ---- workspace layout (float offsets) ----
// wfrag : 65536 bf16 (fragment-ready W)          [0, 32768)
// wlast : 256 fp32 (column 256 of conv_w)        [32768, 33024)
// accA  : [128][256] fp32                        [65792, 98560)
// accX  : [128][256] fp32                        [98560, 131328)
#define WLAST_OFF 32768
#define ACCA_OFF  65792
#define ACCX_OFF  98560

static __device__ __forceinline__ unsigned f2bf_u(float f) {
    unsigned u = __builtin_bit_cast(unsigned, f);
    return (u + 0x7fffu + ((u >> 16) & 1u)) >> 16;                     // RNE
}
// packed bf16 pair via HW cvt (memcpy: __hip_bfloat162 not trivially copyable)
static __device__ __forceinline__ unsigned pkbf(float a, float b) {
    __hip_bfloat162 h = __float22bfloat162_rn(make_float2(a, b));      // a in low 16
    unsigned u; __builtin_memcpy(&u, &h, 4); return u;
}

// Barrier WITHOUT vmcnt drain: LDS produced by reg->ds_write only (no
// global_load_lds), so lgkmcnt(0)+s_barrier is sufficient for LDS visibility
// while prefetch global->reg loads stay in flight across the barrier.
static __device__ __forceinline__ void barrier_lds() {
    asm volatile("s_waitcnt lgkmcnt(0)\n\ts_barrier" ::: "memory");
}

// DPP cross-lane add (all-VALU, no LDS pipe)
template<int CTRL, int RM>
static __device__ __forceinline__ float dpp_add(float x) {
    int yi = __builtin_amdgcn_update_dpp(0, __builtin_bit_cast(int, x), CTRL, RM, 0xF, true);
    return x + __builtin_bit_cast(float, yi);
}
// 32-lane (half-wave) sum; valid in lanes 16-31 / 48-63; lane 31/63 used.
static __device__ __forceinline__ float red32(float x) {
    x = dpp_add<0x121, 0xF>(x);   // row_ror:1
    x = dpp_add<0x122, 0xF>(x);   // row_ror:2
    x = dpp_add<0x124, 0xF>(x);   // row_ror:4
    x = dpp_add<0x128, 0xF>(x);   // row_ror:8
    x = dpp_add<0x142, 0xA>(x);   // row_bcast15 into rows 1,3
    return x;
}

// k_init: fragment-ready bf16 W + wlast + zero accumulators (needed each launch:
// k_main accumulates via atomics).
// A-frag (32x32x16): lane l holds A[o = ot*32 + (l&31)][k = S*16 + (l>>5)*8 + j].
__global__ void k_init(const float* __restrict__ conv_w, float* __restrict__ ws) {
    int bk = blockIdx.x;
    int tid = threadIdx.x;
    int idx = bk * 256 + tid;                   // 0..65535
    int j  = idx & 7;
    int l  = (idx >> 3) & 63;
    int ot = (idx >> 9) & 7;
    int S  = idx >> 12;                         // 0..15
    int o  = ot * 32 + (l & 31);
    int k  = S * 16 + (l >> 5) * 8 + j;
    ((unsigned short*)ws)[idx] = (unsigned short)f2bf_u(conv_w[o * 257 + k]);
    if (idx < 256) ws[WLAST_OFF + idx] = conv_w[idx * 257 + 256];
    ws[ACCA_OFF + idx] = 0.0f;                  // zeroes accA then accX (65536 floats)
}

// k_main: 512 blocks = 2 persistent blocks/CU. Block = (image xb, hw-quarter
// = 256 positions), 4 chunks of 64 hw, round-3 phase structure (3 lgkm-only
// barriers/chunk). The co-resident block fills this block's barrier tails and
// prefetch-vmcnt stalls (TLP instead of the failed round-4 ILP restructure).
// Epilogue x-extraction via b64 quad reads (round-4's proven conflict cut).
__global__ __launch_bounds__(512, 4)   // 4 waves/EU = 16 waves/CU = 2 blocks/CU
void k_main(const float* __restrict__ x1, const float* __restrict__ x2,
            float* __restrict__ ws) {
    int bx = blockIdx.x;               // 0..511
    int xb = bx >> 2;                  // image 0..127
    int qr = bx & 3;                   // hw quarter: 256 positions
    const float* xpi = ((xb < 64) ? x1 : x2) + (size_t)(xb & 63) * (256 * 1024);
    const unsigned short* wfrag = (const unsigned short*)ws;
    float* accA = ws + ACCA_OFF + xb * 256;
    float* accX = ws + ACCX_OFF + xb * 256;

    int tid = threadIdx.x;
    int w = tid >> 6;                  // wave 0..7 (owns o = w*32 .. w*32+31)
    int l = tid & 63;
    int lw = l & 31, q = l >> 5;

    // [S][hw][word] bf16-pair tile; word swizzle: phys = logical ^ ((hw>>4)&1)<<2
    // -> writes 2-way (free), b128 reads ~2-way, S-stride = 2048 B imm.
    __shared__ __align__(16) unsigned sx[16][64][8];   // 32 KB (single buffer)
    __shared__ float sd[64][9];        // dot partials, one col per wave
    __shared__ float swl[256];         // W last column
    __shared__ float scen[256];        // this image's center pixels
    __shared__ float dotf[64];

    int hwi = tid & 15, kc = tid >> 4; // thread: hw hwi*4..+3, channels {2kc,2kc+1}+64s

    // ---- prologue: centers + wlast -> LDS; A-frags -> regs; chunk-0 x -> regs ----
    float cenv = 0.f, wlv = 0.f;
    if (tid < 256) {
        cenv = xpi[(size_t)tid * 1024 + 528];          // x[tid][16][16]
        wlv  = ws[WLAST_OFF + tid];
    }
    const unsigned short* ap = wfrag + (size_t)(w * 64 + l) * 8;
    bf16x8 A[16];
    #pragma unroll
    for (int S = 0; S < 16; ++S)
        A[S] = *(const bf16x8*)(ap + (size_t)S * 4096);

    const float* xbase = xpi + qr * 256 + (size_t)(kc * 2) * 1024 + hwi * 4;
    float4 xv[8];
    #pragma unroll
    for (int s = 0; s < 4; ++s) {
        xv[2 * s]     = *(const float4*)(xbase + (size_t)(64 * s) * 1024);
        xv[2 * s + 1] = *(const float4*)(xbase + (size_t)(64 * s + 1) * 1024);
    }
    if (tid < 256) { scen[tid] = cenv; swl[tid] = wlv; }
    barrier_lds();                                     // scen/swl visible

    int sig = ((lw >> 4) & 1) << 2;                    // same for rows lw, 32+lw
    const unsigned* b0p = &sx[0][lw][(q * 4) ^ sig];
    const unsigned* b1p = &sx[0][32 + lw][(q * 4) ^ sig];

    float sA[16], sX[16];
    #pragma unroll
    for (int r = 0; r < 16; ++r) { sA[r] = 0.f; sX[r] = 0.f; }

    #pragma unroll 1
    for (int t = 0; t < 4; ++t) {
        if (t) barrier_lds();                          // B3: epilogue done with sx

        // ---- convert chunk t + LDS write + center-dot partials ----
        float dotp[4] = {0.f, 0.f, 0.f, 0.f};
        #pragma unroll
        for (int s = 0; s < 4; ++s) {
            float4 e = xv[2 * s], o4 = xv[2 * s + 1];
            int c = kc * 2 + 64 * s;
            float s0 = scen[c], s1 = scen[c + 1];
            dotp[0] += e.x * s0 + o4.x * s1;
            dotp[1] += e.y * s0 + o4.y * s1;
            dotp[2] += e.z * s0 + o4.z * s1;
            dotp[3] += e.w * s0 + o4.w * s1;
            int S  = (kc >> 3) + 4 * s;
            int wd = kc & 7;
            float ee[4] = {e.x, e.y, e.z, e.w};
            float oo[4] = {o4.x, o4.y, o4.z, o4.w};
            #pragma unroll
            for (int j = 0; j < 4; ++j) {
                int jj  = (hwi + j) & 3;               // rotate rows (2-way write)
                int hwr = hwi * 4 + jj;
                sx[S][hwr][wd ^ (((hwr >> 4) & 1) << 2)] = pkbf(ee[jj], oo[jj]);
            }
        }
        // ---- prefetch chunk t+1 (stays in flight across the barriers) ----
        if (t < 3) {
            const float* xn = xbase + (t + 1) * 64;
            #pragma unroll
            for (int s = 0; s < 4; ++s) {
                xv[2 * s]     = *(const float4*)(xn + (size_t)(64 * s) * 1024);
                xv[2 * s + 1] = *(const float4*)(xn + (size_t)(64 * s + 1) * 1024);
            }
        }
        // reduce dot partials across the 4 lanes sharing hwi (lane ^16, ^32)
        #pragma unroll
        for (int j = 0; j < 4; ++j) {
            float v = dotp[j];
            v += __shfl_xor(v, 16, 64);
            v += __shfl_xor(v, 32, 64);
            dotp[j] = v;
        }
        if (l < 16) {
            #pragma unroll
            for (int j = 0; j < 4; ++j) sd[hwi * 4 + j][w] = dotp[j];
        }
        barrier_lds();                                 // B1: sx + sd ready

        if (tid < 64) {                                // wave 0 finalizes dot
            float ssum = 0.f;
            #pragma unroll
            for (int k2 = 0; k2 < 8; ++k2) ssum += sd[tid][k2];
            dotf[tid] = ssum * (1.0f / 256.0f);
        }

        // ---- MFMA: 16 K-steps, pure LDS + registers ----
        f32x16 acc0, acc1;
        #pragma unroll
        for (int e = 0; e < 16; ++e) { acc0[e] = 0.0f; acc1[e] = 0.0f; }
        #pragma unroll
        for (int S = 0; S < 16; ++S) {
            bf16x8 b0, b1;
            __builtin_memcpy(&b0, b0p + S * 512, 16);  // byte off = S*2048 (imm)
            __builtin_memcpy(&b1, b1p + S * 512, 16);
            acc0 = __builtin_amdgcn_mfma_f32_32x32x16_bf16(A[S], b0, acc0, 0, 0, 0);
            acc1 = __builtin_amdgcn_mfma_f32_32x32x16_bf16(A[S], b1, acc1, 0, 0, 0);
        }
        barrier_lds();                                 // B2: dotf ready, sx intact

        // ---- epilogue chunk t: sigmoid + accumulate into sA/sX regs ----
        float dv0 = dotf[lw];
        float dv1 = dotf[32 + lw];
        #pragma unroll
        for (int m = 0; m < 4; ++m) {                  // o-quads: 4 o per b64 read
            int ob = w * 32 + 8 * m + 4 * q;           // even; quad stays in one Si
            int Si = ob >> 4;
            int Wp = ((ob >> 1) & 7) ^ sig;            // even -> b64-aligned
            unsigned u0[2], u1[2];
            __builtin_memcpy(u0, &sx[Si][lw][Wp], 8);
            __builtin_memcpy(u1, &sx[Si][32 + lw][Wp], 8);
            #pragma unroll
            for (int d = 0; d < 4; ++d) {
                int r = 4 * m + d;                     // row = 8m+4q+d (C/D layout)
                int o = ob + d;
                float wl = swl[o];
                float z0 = acc0[r] + wl * dv0;
                float z1 = acc1[r] + wl * dv1;
                float a0s = __builtin_amdgcn_rcpf(1.0f + __expf(-z0));
                float a1s = __builtin_amdgcn_rcpf(1.0f + __expf(-z1));
                unsigned wa = (d & 2) ? u0[1] : u0[0];
                unsigned wb = (d & 2) ? u1[1] : u1[0];
                float xv0 = (d & 1) ? __builtin_bit_cast(float, wa & 0xffff0000u)
                                    : __builtin_bit_cast(float, wa << 16);
                float xv1 = (d & 1) ? __builtin_bit_cast(float, wb & 0xffff0000u)
                                    : __builtin_bit_cast(float, wb << 16);
                sA[r] += a0s + a1s;
                sX[r] += a0s * xv0 + a1s * xv1;
            }
        }
    }

    // ---- final: one DPP reduce + one atomic pair per o for the whole block ----
    // sA[r]/sX[r] indexed r=4m+d correspond to row = 8m+4q+d = (r&3)+8*(r>>2)+4q.
    #pragma unroll
    for (int r = 0; r < 16; ++r) {
        int row = (r & 3) + 8 * (r >> 2) + 4 * q;
        int o = w * 32 + row;
        float rA = red32(sA[r]);
        float rX = red32(sX[r]);
        if (lw == 31) {                                // lanes 31,63 hold sums
            atomicAdd(&accA[o], rA);
            atomicAdd(&accX[o], rX);
        }
    }
}

// out[b,o] = accX0/(accA0+eps) + accX1/(accA1+eps)
__global__ void k_out(const float* __restrict__ ws, float* __restrict__ out) {
    int idx = blockIdx.x * 256 + threadIdx.x;     // b*256 + o
    int b = idx >> 8, o = idx & 255;
    float a0 = ws[ACCA_OFF + b * 256 + o];
    float p0 = ws[ACCX_OFF + b * 256 + o];
    float a1 = ws[ACCA_OFF + (64 + b) * 256 + o];
    float p1 = ws[ACCX_OFF + (64 + b) * 256 + o];
    out[idx] = p0 / (a0 + 1e-8f) + p1 / (a1 + 1e-8f);
}

extern "C" void kernel_launch(void* const* d_in, const int* in_sizes, int n_in,
                              void* d_out, int out_size, void* d_ws, size_t ws_size,
                              hipStream_t stream) {
    const float* x1     = (const float*)d_in[0];
    const float* x2     = (const float*)d_in[1];
    const float* conv_w = (const float*)d_in[2];
    // d_in[3..6] (caLayer params) are dead: softmax over a size-1 axis == 1.
    float* ws  = (float*)d_ws;
    float* out = (float*)d_out;

    k_init<<<256, 256, 0, stream>>>(conv_w, ws);
    k_main<<<512, 512, 0, stream>>>(x1, x2, ws);
    k_out<<<64, 256, 0, stream>>>(ws, out);
}

// Round 6
// 199.260 us; speedup vs baseline: 1.1267x; 1.1267x over previous
//
#include <hip/hip_runtime.h>
#include <hip/hip_bf16.h>
#include <math.h>

// dtypes for MFMA
typedef __bf16 bf16x8 __attribute__((ext_vector_type(8)));
typedef float  f32x16 __attribute__((ext_vector_type(16)));

// ---- workspace layout (float offsets) ----
// wfrag : 65536 bf16 (fragment-ready W)          [0, 32768)
// wlast : 256 fp32 (column 256 of conv_w)        [32768, 33024)
// cen   : [128][256] fp32 center pixels          [33024, 65792)
// accA  : [128][256] fp32                        [65792, 98560)
// accX  : [128][256] fp32                        [98560, 131328)
#define WLAST_OFF 32768
#define CEN_OFF   33024
#define ACCA_OFF  65792
#define ACCX_OFF  98560

static __device__ __forceinline__ unsigned f2bf_u(float f) {
    unsigned u = __builtin_bit_cast(unsigned, f);
    return (u + 0x7fffu + ((u >> 16) & 1u)) >> 16;                     // RNE
}
// packed bf16 pair via HW cvt (memcpy: __hip_bfloat162 not trivially copyable)
static __device__ __forceinline__ unsigned pkbf(float a, float b) {
    __hip_bfloat162 h = __float22bfloat162_rn(make_float2(a, b));      // a in low 16
    unsigned u; __builtin_memcpy(&u, &h, 4); return u;
}

// Barrier WITHOUT vmcnt drain: LDS produced by reg->ds_write only (no
// global_load_lds), so lgkmcnt(0)+s_barrier is sufficient for LDS visibility
// while prefetch global->reg loads stay in flight across the barrier.
static __device__ __forceinline__ void barrier_lds() {
    asm volatile("s_waitcnt lgkmcnt(0)\n\ts_barrier" ::: "memory");
}

// DPP cross-lane add (all-VALU, no LDS pipe)
template<int CTRL, int RM>
static __device__ __forceinline__ float dpp_add(float x) {
    int yi = __builtin_amdgcn_update_dpp(0, __builtin_bit_cast(int, x), CTRL, RM, 0xF, true);
    return x + __builtin_bit_cast(float, yi);
}
// 32-lane (half-wave) sum; valid in lanes 16-31 / 48-63; lane 31/63 used.
static __device__ __forceinline__ float red32(float x) {
    x = dpp_add<0x121, 0xF>(x);   // row_ror:1
    x = dpp_add<0x122, 0xF>(x);   // row_ror:2
    x = dpp_add<0x124, 0xF>(x);   // row_ror:4
    x = dpp_add<0x128, 0xF>(x);   // row_ror:8
    x = dpp_add<0x142, 0xA>(x);   // row_bcast15 into rows 1,3
    return x;
}

// k_init: fragment-ready bf16 W + wlast + center extraction + zero accumulators.
// A-frag (32x32x16): lane l holds A[o = ot*32 + (l&31)][k = S*16 + (l>>5)*8 + j].
__global__ void k_init(const float* __restrict__ x1, const float* __restrict__ x2,
                       const float* __restrict__ conv_w, float* __restrict__ ws) {
    int bk = blockIdx.x;
    int tid = threadIdx.x;
    if (bk < 256) {
        int idx = bk * 256 + tid;                   // 0..65535
        int j  = idx & 7;
        int l  = (idx >> 3) & 63;
        int ot = (idx >> 9) & 7;
        int S  = idx >> 12;                         // 0..15
        int o  = ot * 32 + (l & 31);
        int k  = S * 16 + (l >> 5) * 8 + j;
        ((unsigned short*)ws)[idx] = (unsigned short)f2bf_u(conv_w[o * 257 + k]);
        if (idx < 256) ws[WLAST_OFF + idx] = conv_w[idx * 257 + 256];
        ws[ACCA_OFF + idx] = 0.0f;                  // zeroes accA then accX (65536 floats)
    } else {
        int xb = bk - 256;                          // 0..127: extract centers
        const float* xp = ((xb < 64) ? x1 : x2) + (size_t)(xb & 63) * (256 * 1024);
        ws[CEN_OFF + xb * 256 + tid] = xp[(size_t)tid * 1024 + 528];   // (16,16)
    }
}

// k_main: 512 blocks = 2 co-resident blocks/CU (the TLP retest, now spill-free).
// Block = (image xb, hw-quarter), 4 chunks of 64 hw, R3 phase structure.
// Register diet vs R3: A held as a rolling 4-slot ring refilled from L2 inside
// the MFMA loop (16 regs, not 64); per-chunk DPP reduce+atomics (sA/sX not
// persistent). xv prefetch issued AFTER the MFMA loop so the in-order vmcnt
// queue never makes an A-load wait behind an HBM xv-load.
__global__ __launch_bounds__(512, 4)   // cap 128 unified regs -> 2 blocks/CU
void k_main(const float* __restrict__ x1, const float* __restrict__ x2,
            float* __restrict__ ws) {
    int bx = blockIdx.x;               // 0..511
    int xb = bx >> 2;                  // image 0..127
    int qr = bx & 3;                   // hw quarter: 256 positions
    const float* xpi = ((xb < 64) ? x1 : x2) + (size_t)(xb & 63) * (256 * 1024);
    const unsigned short* wfrag = (const unsigned short*)ws;
    float* accA = ws + ACCA_OFF + xb * 256;
    float* accX = ws + ACCX_OFF + xb * 256;

    int tid = threadIdx.x;
    int w = tid >> 6;                  // wave 0..7 (owns o = w*32 .. w*32+31)
    int l = tid & 63;
    int lw = l & 31, q = l >> 5;

    // [S][hw][word] bf16-pair tile; word swizzle: phys = logical ^ ((hw>>4)&1)<<2
    __shared__ __align__(16) unsigned sx[16][64][8];   // 32 KB (single buffer)
    __shared__ float sd[64][9];        // dot partials, one col per wave
    __shared__ float swl[256];         // W last column
    __shared__ float scen[256];        // this image's center pixels
    __shared__ float dotf[64];

    int hwi = tid & 15, kc = tid >> 4; // thread: hw hwi*4..+3, channels {2kc,2kc+1}+64s

    // ---- prologue: centers(compact ws)+wlast -> LDS; Ar[0..3]; chunk-0 x ----
    float cenv = 0.f, wlv = 0.f;
    if (tid < 256) {
        cenv = ws[CEN_OFF + xb * 256 + tid];
        wlv  = ws[WLAST_OFF + tid];
    }
    const float* xbase = xpi + qr * 256 + (size_t)(kc * 2) * 1024 + hwi * 4;
    float4 xv[8];
    #pragma unroll
    for (int s = 0; s < 4; ++s) {
        xv[2 * s]     = *(const float4*)(xbase + (size_t)(64 * s) * 1024);
        xv[2 * s + 1] = *(const float4*)(xbase + (size_t)(64 * s + 1) * 1024);
    }
    const unsigned short* ap = wfrag + (size_t)(w * 64 + l) * 8;
    bf16x8 Ar[4];
    #pragma unroll
    for (int k = 0; k < 4; ++k)
        Ar[k] = *(const bf16x8*)(ap + (size_t)k * 4096);
    if (tid < 256) { scen[tid] = cenv; swl[tid] = wlv; }
    barrier_lds();                                     // scen/swl visible

    int sig = ((lw >> 4) & 1) << 2;                    // same for rows lw, 32+lw
    const unsigned* b0p = &sx[0][lw][(q * 4) ^ sig];
    const unsigned* b1p = &sx[0][32 + lw][(q * 4) ^ sig];

    #pragma unroll 1
    for (int t = 0; t < 4; ++t) {
        if (t) barrier_lds();                          // B3: epilogue done with sx

        // ---- convert chunk t + LDS write + center-dot partials ----
        float dotp[4] = {0.f, 0.f, 0.f, 0.f};
        #pragma unroll
        for (int s = 0; s < 4; ++s) {
            float4 e = xv[2 * s], o4 = xv[2 * s + 1];
            int c = kc * 2 + 64 * s;
            float s0 = scen[c], s1 = scen[c + 1];
            dotp[0] += e.x * s0 + o4.x * s1;
            dotp[1] += e.y * s0 + o4.y * s1;
            dotp[2] += e.z * s0 + o4.z * s1;
            dotp[3] += e.w * s0 + o4.w * s1;
            int S  = (kc >> 3) + 4 * s;
            int wd = kc & 7;
            float ee[4] = {e.x, e.y, e.z, e.w};
            float oo[4] = {o4.x, o4.y, o4.z, o4.w};
            #pragma unroll
            for (int j = 0; j < 4; ++j) {
                int jj  = (hwi + j) & 3;               // rotate rows (2-way write)
                int hwr = hwi * 4 + jj;
                sx[S][hwr][wd ^ (((hwr >> 4) & 1) << 2)] = pkbf(ee[jj], oo[jj]);
            }
        }
        // reduce dot partials across the 4 lanes sharing hwi (lane ^16, ^32)
        #pragma unroll
        for (int j = 0; j < 4; ++j) {
            float v = dotp[j];
            v += __shfl_xor(v, 16, 64);
            v += __shfl_xor(v, 32, 64);
            dotp[j] = v;
        }
        if (l < 16) {
            #pragma unroll
            for (int j = 0; j < 4; ++j) sd[hwi * 4 + j][w] = dotp[j];
        }
        barrier_lds();                                 // B1: sx + sd ready

        if (tid < 64) {                                // wave 0 finalizes dot
            float ssum = 0.f;
            #pragma unroll
            for (int k2 = 0; k2 < 8; ++k2) ssum += sd[tid][k2];
            dotf[tid] = ssum * (1.0f / 256.0f);
        }

        // ---- MFMA: 16 K-steps; A-ring refilled from L2 after each use ----
        f32x16 acc0, acc1;
        #pragma unroll
        for (int e = 0; e < 16; ++e) { acc0[e] = 0.0f; acc1[e] = 0.0f; }
        #pragma unroll
        for (int S = 0; S < 16; ++S) {
            bf16x8 b0, b1;
            __builtin_memcpy(&b0, b0p + S * 512, 16);  // byte off = S*2048 (imm)
            __builtin_memcpy(&b1, b1p + S * 512, 16);
            acc0 = __builtin_amdgcn_mfma_f32_32x32x16_bf16(Ar[S & 3], b0, acc0, 0, 0, 0);
            acc1 = __builtin_amdgcn_mfma_f32_32x32x16_bf16(Ar[S & 3], b1, acc1, 0, 0, 0);
            // refill the slot just consumed with A[(S+4)&15] (wraps to next chunk)
            Ar[S & 3] = *(const bf16x8*)(ap + (size_t)((S + 4) & 15) * 4096);
        }
        // ---- prefetch chunk t+1 AFTER all A-issues (in-order vmcnt!) ----
        if (t < 3) {
            const float* xn = xbase + (t + 1) * 64;
            #pragma unroll
            for (int s = 0; s < 4; ++s) {
                xv[2 * s]     = *(const float4*)(xn + (size_t)(64 * s) * 1024);
                xv[2 * s + 1] = *(const float4*)(xn + (size_t)(64 * s + 1) * 1024);
            }
        }
        barrier_lds();                                 // B2: dotf ready, sx intact

        // ---- epilogue chunk t: sigmoid; x via b64 quads; reduce + atomics ----
        float dv0 = dotf[lw];
        float dv1 = dotf[32 + lw];
        #pragma unroll
        for (int m = 0; m < 4; ++m) {                  // o-quads: 4 o per b64 read
            int ob = w * 32 + 8 * m + 4 * q;           // even; quad stays in one Si
            int Si = ob >> 4;
            int Wp = ((ob >> 1) & 7) ^ sig;            // even -> b64-aligned
            unsigned u0[2], u1[2];
            __builtin_memcpy(u0, &sx[Si][lw][Wp], 8);
            __builtin_memcpy(u1, &sx[Si][32 + lw][Wp], 8);
            #pragma unroll
            for (int d = 0; d < 4; ++d) {
                int r = 4 * m + d;                     // row = 8m+4q+d (C/D layout)
                int o = ob + d;
                float wl = swl[o];
                float z0 = acc0[r] + wl * dv0;
                float z1 = acc1[r] + wl * dv1;
                float a0s = __builtin_amdgcn_rcpf(1.0f + __expf(-z0));
                float a1s = __builtin_amdgcn_rcpf(1.0f + __expf(-z1));
                unsigned wa = (d & 2) ? u0[1] : u0[0];
                unsigned wb = (d & 2) ? u1[1] : u1[0];
                float xv0 = (d & 1) ? __builtin_bit_cast(float, wa & 0xffff0000u)
                                    : __builtin_bit_cast(float, wa << 16);
                float xv1 = (d & 1) ? __builtin_bit_cast(float, wb & 0xffff0000u)
                                    : __builtin_bit_cast(float, wb << 16);
                float vA = red32(a0s + a1s);
                float vX = red32(a0s * xv0 + a1s * xv1);
                if (lw == 31) {                        // lanes 31,63 hold sums
                    atomicAdd(&accA[o], vA);
                    atomicAdd(&accX[o], vX);
                }
            }
        }
    }
}

// out[b,o] = accX0/(accA0+eps) + accX1/(accA1+eps)
__global__ void k_out(const float* __restrict__ ws, float* __restrict__ out) {
    int idx = blockIdx.x * 256 + threadIdx.x;     // b*256 + o
    int b = idx >> 8, o = idx & 255;
    float a0 = ws[ACCA_OFF + b * 256 + o];
    float p0 = ws[ACCX_OFF + b * 256 + o];
    float a1 = ws[ACCA_OFF + (64 + b) * 256 + o];
    float p1 = ws[ACCX_OFF + (64 + b) * 256 + o];
    out[idx] = p0 / (a0 + 1e-8f) + p1 / (a1 + 1e-8f);
}

extern "C" void kernel_launch(void* const* d_in, const int* in_sizes, int n_in,
                              void* d_out, int out_size, void* d_ws, size_t ws_size,
                              hipStream_t stream) {
    const float* x1     = (const float*)d_in[0];
    const float* x2     = (const float*)d_in[1];
    const float* conv_w = (const float*)d_in[2];
    // d_in[3..6] (caLayer params) are dead: softmax over a size-1 axis == 1.
    float* ws  = (float*)d_ws;
    float* out = (float*)d_out;

    k_init<<<384, 256, 0, stream>>>(x1, x2, conv_w, ws);
    k_main<<<512, 512, 0, stream>>>(x1, x2, ws);
    k_out<<<64, 256, 0, stream>>>(ws, out);
}

// Round 9
// 165.248 us; speedup vs baseline: 1.3586x; 1.2058x over previous
//
#include <hip/hip_runtime.h>
#include <hip/hip_bf16.h>
#include <math.h>

// dtypes for MFMA
typedef __bf16 bf16x8 __attribute__((ext_vector_type(8)));
typedef float  f32x16 __attribute__((ext_vector_type(16)));

// ---- workspace layout (float offsets) ----
// Total 131328 floats = EXACTLY the proven R0-R6 footprint (R7 grew it to
// 164096 and the container died both rounds -- suspected ws overflow).
// accA  : [128][256] fp32                        [0, 32768)
// accX  : [128][256] fp32                        [32768, 65536)
// wlast : 256 fp32 (column 256 of conv_w)        [65536, 65792)
// wf32  : 65536 f32 (fragment-ordered conv_w)    [65792, 131328)
#define ACCA_OFF  0
#define ACCX_OFF  32768
#define WLAST_OFF 65536
#define WF_OFF    65792

// packed bf16 pair via HW cvt (memcpy: __hip_bfloat162 not trivially copyable)
static __device__ __forceinline__ unsigned pkbf(float a, float b) {
    __hip_bfloat162 h = __float22bfloat162_rn(make_float2(a, b));      // a in low 16
    unsigned u; __builtin_memcpy(&u, &h, 4); return u;
}

// Barrier WITHOUT vmcnt drain: LDS produced by reg->ds_write only (no
// global_load_lds), so lgkmcnt(0)+s_barrier is sufficient for LDS visibility
// while prefetch global->reg loads stay in flight across the barrier.
static __device__ __forceinline__ void barrier_lds() {
    asm volatile("s_waitcnt lgkmcnt(0)\n\ts_barrier" ::: "memory");
}

// DPP cross-lane add (all-VALU, no LDS pipe)
template<int CTRL, int RM>
static __device__ __forceinline__ float dpp_add(float x) {
    int yi = __builtin_amdgcn_update_dpp(0, __builtin_bit_cast(int, x), CTRL, RM, 0xF, true);
    return x + __builtin_bit_cast(float, yi);
}
// 32-lane (half-wave) sum; valid in lanes 16-31 / 48-63; lane 31/63 used.
static __device__ __forceinline__ float red32(float x) {
    x = dpp_add<0x121, 0xF>(x);   // row_ror:1
    x = dpp_add<0x122, 0xF>(x);   // row_ror:2
    x = dpp_add<0x124, 0xF>(x);   // row_ror:4
    x = dpp_add<0x128, 0xF>(x);   // row_ror:8
    x = dpp_add<0x142, 0xA>(x);   // row_bcast15 into rows 1,3
    return x;
}

// k_init: fragment-ordered f32 W + wlast + zero accumulators. 256 blocks
// (proven shape). A-frag (32x32x16): lane l holds
// A[o = ot*32 + (l&31)][k = S*16 + (l>>5)*8 + j].
__global__ void k_init(const float* __restrict__ conv_w, float* __restrict__ ws) {
    int idx = blockIdx.x * 256 + threadIdx.x;   // 0..65535
    int j  = idx & 7;
    int l  = (idx >> 3) & 63;
    int ot = (idx >> 9) & 7;
    int S  = idx >> 12;                         // 0..15
    int o  = ot * 32 + (l & 31);
    int k  = S * 16 + (l >> 5) * 8 + j;
    ws[WF_OFF + idx] = conv_w[o * 257 + k];     // f32, fragment order
    if (idx < 256) ws[WLAST_OFF + idx] = conv_w[idx * 257 + 256];
    ws[idx] = 0.0f;                             // zeroes accA then accX
}

// k_main: 256 blocks = 1/CU; block = (image xb, hw-half), 8 chunks of 64 hw.
// ALGEBRAIC FUSION: z = (W + wlast*cen^T/256) . x  -- the center-dot is a
// rank-1 weight update folded into per-image bf16 A-fragments in the prologue
// (f32 fold, one bf16 rounding). The whole dot pipeline (dot FMAs, shuffles,
// sd/dotf, wave0 finalize, one barrier, epilogue wl*dv FMAs) is deleted.
// Chunk = [convert|prefetch] B1 [MFMA + epilogue, both READ sx] B0(next).
// Centers loaded directly from x (R2/R3-proven pattern), staged in 1 KB LDS.
__global__ __launch_bounds__(512, 2)   // cap 256 regs -> no spill (R5/R6 lesson)
void k_main(const float* __restrict__ x1, const float* __restrict__ x2,
            float* __restrict__ ws) {
    int bx = blockIdx.x;               // 0..255
    int xb = bx >> 1;                  // image 0..127
    int half = bx & 1;                 // hw half: 512 positions
    const float* xpi = ((xb < 64) ? x1 : x2) + (size_t)(xb & 63) * (256 * 1024);
    float* accA = ws + ACCA_OFF + xb * 256;
    float* accX = ws + ACCX_OFF + xb * 256;

    int tid = threadIdx.x;
    int w = tid >> 6;                  // wave 0..7 (owns o = w*32 .. w*32+31)
    int l = tid & 63;
    int lw = l & 31, q = l >> 5;

    // [S][hw][word] bf16-pair tile; word swizzle: phys = logical ^ ((hw>>4)&1)<<2
    // -> writes 2-way (free), b128 reads ~4-way, S-stride = 2048 B imm.
    __shared__ __align__(16) unsigned sx[16][64][8];   // 32 KB
    __shared__ __align__(16) float scen[256];          // center pixels (fold input)

    int hwi = tid & 15, kc = tid >> 4; // thread: hw hwi*4..+3, channels {2kc,2kc+1}+64s

    // ---- prologue: chunk-0 x (HBM, issue first); centers -> LDS; W_eff fold ----
    const float* xbase = xpi + half * 512 + (size_t)(kc * 2) * 1024 + hwi * 4;
    float4 xv[8];
    #pragma unroll
    for (int s = 0; s < 4; ++s) {
        xv[2 * s]     = *(const float4*)(xbase + (size_t)(64 * s) * 1024);
        xv[2 * s + 1] = *(const float4*)(xbase + (size_t)(64 * s + 1) * 1024);
    }
    float cenv = 0.f;
    if (tid < 256) cenv = xpi[(size_t)tid * 1024 + 528];   // x[tid][16][16]
    float wl = ws[WLAST_OFF + w * 32 + lw] * (1.0f / 256.0f);
    if (tid < 256) scen[tid] = cenv;
    barrier_lds();                                     // scen visible

    // W_eff[o][k] = W[o][k] + wlast[o]*cen[k]/256, rounded to bf16 once.
    // Lane l, wave w: o = w*32+lw, k = S*16 + q*8 + j.
    const float* wf = ws + WF_OFF + (size_t)(w * 512 + l * 8);   // + S*4096
    bf16x8 A[16];
    #pragma unroll
    for (int S = 0; S < 16; ++S) {
        float4 w0 = *(const float4*)(wf + (size_t)S * 4096);
        float4 w1 = *(const float4*)(wf + (size_t)S * 4096 + 4);
        const float* cp = scen + S * 16 + q * 8;       // LDS (broadcast per q)
        float4 c0 = *(const float4*)(cp);
        float4 c1 = *(const float4*)(cp + 4);
        unsigned pw[4];
        pw[0] = pkbf(fmaf(wl, c0.x, w0.x), fmaf(wl, c0.y, w0.y));
        pw[1] = pkbf(fmaf(wl, c0.z, w0.z), fmaf(wl, c0.w, w0.w));
        pw[2] = pkbf(fmaf(wl, c1.x, w1.x), fmaf(wl, c1.y, w1.y));
        pw[3] = pkbf(fmaf(wl, c1.z, w1.z), fmaf(wl, c1.w, w1.w));
        __builtin_memcpy(&A[S], pw, 16);
    }

    int sig = ((lw >> 4) & 1) << 2;                    // same for rows lw, 32+lw
    const unsigned* b0p = &sx[0][lw][(q * 4) ^ sig];
    const unsigned* b1p = &sx[0][32 + lw][(q * 4) ^ sig];

    float sA[16], sX[16];
    #pragma unroll
    for (int r = 0; r < 16; ++r) { sA[r] = 0.f; sX[r] = 0.f; }

    #pragma unroll 1
    for (int t = 0; t < 8; ++t) {
        if (t) barrier_lds();                          // B0: prev readers done with sx

        // ---- convert chunk t -> sx (pure pack + ds_write; no dot math) ----
        #pragma unroll
        for (int s = 0; s < 4; ++s) {
            float4 e = xv[2 * s], o4 = xv[2 * s + 1];
            int S  = (kc >> 3) + 4 * s;
            int wd = kc & 7;
            float ee[4] = {e.x, e.y, e.z, e.w};
            float oo[4] = {o4.x, o4.y, o4.z, o4.w};
            #pragma unroll
            for (int j = 0; j < 4; ++j) {
                int jj  = (hwi + j) & 3;               // rotate rows (2-way write)
                int hwr = hwi * 4 + jj;
                sx[S][hwr][wd ^ (((hwr >> 4) & 1) << 2)] = pkbf(ee[jj], oo[jj]);
            }
        }
        // ---- prefetch chunk t+1 (in flight across barrier + MFMA + epilogue) ----
        if (t < 7) {
            const float* xn = xbase + (t + 1) * 64;
            #pragma unroll
            for (int s = 0; s < 4; ++s) {
                xv[2 * s]     = *(const float4*)(xn + (size_t)(64 * s) * 1024);
                xv[2 * s + 1] = *(const float4*)(xn + (size_t)(64 * s + 1) * 1024);
            }
        }
        barrier_lds();                                 // B1: sx ready

        // ---- MFMA: 16 K-steps, pure LDS + registers ----
        f32x16 acc0, acc1;
        #pragma unroll
        for (int e = 0; e < 16; ++e) { acc0[e] = 0.0f; acc1[e] = 0.0f; }
        #pragma unroll
        for (int S = 0; S < 16; ++S) {
            bf16x8 b0, b1;
            __builtin_memcpy(&b0, b0p + S * 512, 16);  // byte off = S*2048 (imm)
            __builtin_memcpy(&b1, b1p + S * 512, 16);
            acc0 = __builtin_amdgcn_mfma_f32_32x32x16_bf16(A[S], b0, acc0, 0, 0, 0);
            acc1 = __builtin_amdgcn_mfma_f32_32x32x16_bf16(A[S], b1, acc1, 0, 0, 0);
        }

        // ---- epilogue chunk t (READS sx only -- no barrier after MFMA):
        //      z = acc; sigmoid; x via b64 quads; accumulate sA/sX regs ----
        #pragma unroll
        for (int m = 0; m < 4; ++m) {                  // o-quads: 4 o per b64 read
            int ob = w * 32 + 8 * m + 4 * q;           // even; quad stays in one Si
            int Si = ob >> 4;
            int Wp = ((ob >> 1) & 7) ^ sig;            // even -> b64-aligned
            unsigned u0[2], u1[2];
            __builtin_memcpy(u0, &sx[Si][lw][Wp], 8);
            __builtin_memcpy(u1, &sx[Si][32 + lw][Wp], 8);
            #pragma unroll
            for (int d = 0; d < 4; ++d) {
                int r = 4 * m + d;                     // acc idx; row = 8m+4q+d
                float a0s = __builtin_amdgcn_rcpf(1.0f + __expf(-acc0[r]));
                float a1s = __builtin_amdgcn_rcpf(1.0f + __expf(-acc1[r]));
                unsigned wa = (d & 2) ? u0[1] : u0[0];
                unsigned wb = (d & 2) ? u1[1] : u1[0];
                float xv0 = (d & 1) ? __builtin_bit_cast(float, wa & 0xffff0000u)
                                    : __builtin_bit_cast(float, wa << 16);
                float xv1 = (d & 1) ? __builtin_bit_cast(float, wb & 0xffff0000u)
                                    : __builtin_bit_cast(float, wb << 16);
                sA[r] += a0s + a1s;
                sX[r] += a0s * xv0 + a1s * xv1;
            }
        }
    }

    // ---- final: one DPP reduce + one atomic pair per o for the whole block ----
    // sA[r]/sX[r] with r=4m+d map to row = d+8m+4q = (r&3)+8*(r>>2)+4q.
    #pragma unroll
    for (int r = 0; r < 16; ++r) {
        int row = (r & 3) + 8 * (r >> 2) + 4 * q;
        int o = w * 32 + row;
        float rA = red32(sA[r]);
        float rX = red32(sX[r]);
        if (lw == 31) {                                // lanes 31,63 hold sums
            atomicAdd(&accA[o], rA);
            atomicAdd(&accX[o], rX);
        }
    }
}

// out[b,o] = accX0/(accA0+eps) + accX1/(accA1+eps)
__global__ void k_out(const float* __restrict__ ws, float* __restrict__ out) {
    int idx = blockIdx.x * 256 + threadIdx.x;     // b*256 + o
    int b = idx >> 8, o = idx & 255;
    float a0 = ws[ACCA_OFF + b * 256 + o];
    float p0 = ws[ACCX_OFF + b * 256 + o];
    float a1 = ws[ACCA_OFF + (64 + b) * 256 + o];
    float p1 = ws[ACCX_OFF + (64 + b) * 256 + o];
    out[idx] = p0 / (a0 + 1e-8f) + p1 / (a1 + 1e-8f);
}

extern "C" void kernel_launch(void* const* d_in, const int* in_sizes, int n_in,
                              void* d_out, int out_size, void* d_ws, size_t ws_size,
                              hipStream_t stream) {
    const float* x1     = (const float*)d_in[0];
    const float* x2     = (const float*)d_in[1];
    const float* conv_w = (const float*)d_in[2];
    // d_in[3..6] (caLayer params) are dead: softmax over a size-1 axis == 1.
    float* ws  = (float*)d_ws;
    float* out = (float*)d_out;

    k_init<<<256, 256, 0, stream>>>(conv_w, ws);
    k_main<<<256, 512, 0, stream>>>(x1, x2, ws);
    k_out<<<64, 256, 0, stream>>>(ws, out);
}